// Round 7
// baseline (273.990 us; speedup 1.0000x reference)
//
#include <hip/hip_runtime.h>

// ---------------------------------------------------------------------------
// SimpleGCN: 2x GCNConv (self-loops, symmetric norm) + mean pool + MLP head
// N=100000 nodes, E=1.6M edges, IN=128, HID=64, G=128 graphs, NCLS=10
//
// Round 6 change: R5 showed aggregate is fetch-service-bound: FETCH_SIZE
// 195MB = 8 XCDs x ~190k unique 128B lines (each 256B row = 2 lines; every
// XCD's random gathers cover ~all rows). Channel-split the aggregate:
// half = blockIdx.x & 1 selects which 128B HALF-row (32 channels) a block
// gathers. Under round-robin block->XCD dispatch, even XCDs only touch
// low half-lines and odd XCDs high half-lines -> per-XCD unique footprint
// halves -> FETCH ~130MB. Pure locality heuristic: correctness does not
// depend on the mapping. Wave = (node, half); lanes = 2 edge-parities x 32
// channels; one wave-wide load = 2 edges' half-lines; 16 edges in flight.
// ---------------------------------------------------------------------------

#define TPB 256
#define FIX_SCALE 16777216.0f   // 2^24
#define BKT_BITS 8              // bucket = 256 nodes
#define PART_BLOCKS 256         // blocks in hist/partition passes

__device__ __forceinline__ int lower_bound_i(const int* __restrict__ a, int n, int key) {
    int lo = 0, hi = n;
    while (lo < hi) {
        int mid = (lo + hi) >> 1;
        if (a[mid] < key) lo = mid + 1; else hi = mid;
    }
    return lo;
}

// --- A. per-block bucket histogram ------------------------------------------
__global__ __launch_bounds__(256) void k_histA(const int* __restrict__ col, int E, int CH,
                                               int K, int* __restrict__ bh) {
    __shared__ int hist[512];
    int b = blockIdx.x, t = threadIdx.x;
    for (int i = t; i < K; i += 256) hist[i] = 0;
    __syncthreads();
    int s = b * CH, e = min(E, s + CH);
    for (int i = s + t; i < e; i += 256) atomicAdd(&hist[col[i] >> BKT_BITS], 1);
    __syncthreads();
    for (int i = t; i < K; i += 256) bh[i * PART_BLOCKS + b] = hist[i];
}

// --- scan (1024 elems per block) ---------------------------------------------
__global__ void k_scan_partial(const int* __restrict__ cnt, int* __restrict__ bsums, int n) {
    __shared__ int red[4];
    int b = blockIdx.x, t = threadIdx.x;
    int base = b * 1024;
    int s = 0;
#pragma unroll
    for (int i = 0; i < 4; i++) {
        int idx = base + t + i * TPB;
        if (idx < n) s += cnt[idx];
    }
#pragma unroll
    for (int off = 32; off > 0; off >>= 1) s += __shfl_down(s, off);
    if ((t & 63) == 0) red[t >> 6] = s;
    __syncthreads();
    if (t == 0) bsums[b] = red[0] + red[1] + red[2] + red[3];
}

__global__ void k_scan_bsums(int* __restrict__ bsums, int nb) {
    int l = threadIdx.x;
    int carry = 0;
    for (int base = 0; base < nb; base += 64) {
        int i = base + l;
        int v = (i < nb) ? bsums[i] : 0;
        int orig = v;
#pragma unroll
        for (int off = 1; off < 64; off <<= 1) {
            int x = __shfl_up(v, off);
            if (l >= off) v += x;
        }
        if (i < nb) bsums[i] = v - orig + carry;  // exclusive + carry
        carry += __shfl(v, 63);
    }
}

__global__ void k_scan_final(const int* __restrict__ cnt, const int* __restrict__ boffs,
                             int* __restrict__ offs, int n) {
    __shared__ int ts[TPB];
    int b = blockIdx.x, t = threadIdx.x;
    int base = b * 1024 + 4 * t;
    int v[4]; int s = 0;
#pragma unroll
    for (int i = 0; i < 4; i++) {
        int idx = base + i;
        v[i] = (idx < n) ? cnt[idx] : 0;
        s += v[i];
    }
    ts[t] = s; __syncthreads();
    for (int off = 1; off < 256; off <<= 1) {
        int x = (t >= off) ? ts[t - off] : 0;
        __syncthreads();
        ts[t] += x;
        __syncthreads();
    }
    int run = ts[t] - s + boffs[b];
#pragma unroll
    for (int i = 0; i < 4; i++) {
        int idx = base + i;
        if (idx < n) offs[idx] = run;
        run += v[i];
    }
}

// --- C. partition edges by bucket (LDS cursors, no global atomics) ----------
__global__ __launch_bounds__(256) void k_partB(const int* __restrict__ row,
                                               const int* __restrict__ col,
                                               const float* __restrict__ ew,
                                               const int* __restrict__ bhs,
                                               int E, int CH, int K,
                                               int2* __restrict__ part2,
                                               int* __restrict__ partc) {
    __shared__ int cur[512];
    int b = blockIdx.x, t = threadIdx.x;
    for (int i = t; i < K; i += 256) cur[i] = bhs[i * PART_BLOCKS + b];
    __syncthreads();
    int s = b * CH, e = min(E, s + CH);
    for (int i = s + t; i < e; i += 256) {
        int c = col[i];
        int pos = atomicAdd(&cur[c >> BKT_BITS], 1);
        part2[pos] = make_int2(row[i], __float_as_int(ew[i]));
        partc[pos] = c;
    }
}

// --- D. per-bucket CSR finalize ----------------------------------------------
__global__ __launch_bounds__(256) void k_csrC(const int2* __restrict__ part2,
                                              const int* __restrict__ partc,
                                              const int* __restrict__ bhs,
                                              int K, int N, int E,
                                              int* __restrict__ offs, int* __restrict__ cnt,
                                              float* __restrict__ dinv,
                                              int2* __restrict__ csr) {
    __shared__ int lcnt[256];
    __shared__ unsigned lew[256];
    __shared__ int lcur[256];
    __shared__ int ts[256];
    int k = blockIdx.x, t = threadIdx.x;
    int n0 = k << BKT_BITS;
    lcnt[t] = 0; lew[t] = 0;
    __syncthreads();
    int estart = bhs[k * PART_BLOCKS];
    int eend   = (k + 1 < K) ? bhs[(k + 1) * PART_BLOCKS] : E;
    for (int i = estart + t; i < eend; i += 256) {
        int c = partc[i] - n0;
        atomicAdd(&lcnt[c], 1);
        float w = __int_as_float(part2[i].y);
        atomicAdd(&lew[c], (unsigned)(w * FIX_SCALE + 0.5f));
    }
    __syncthreads();
    int myc = lcnt[t];
    ts[t] = myc; __syncthreads();
    for (int off = 1; off < 256; off <<= 1) {
        int x = (t >= off) ? ts[t - off] : 0;
        __syncthreads();
        ts[t] += x;
        __syncthreads();
    }
    int goff = estart + ts[t] - myc;   // global CSR offset for node n0+t
    int node = n0 + t;
    if (node < N) {
        offs[node] = goff;
        cnt[node]  = myc;
        float deg = 1.0f + (float)((double)lew[t] * (1.0 / 16777216.0));
        dinv[node] = 1.0f / sqrtf(deg);
    }
    lcur[t] = goff;
    __syncthreads();
    for (int i = estart + t; i < eend; i += 256) {
        int c = partc[i] - n0;
        int pos = atomicAdd(&lcur[c], 1);
        csr[pos] = part2[i];
    }
}

// --- matmul: H'[n,64] = dinv (.) (X[n,K] @ W[K,64]) -------------------------
template <int K>
__global__ __launch_bounds__(256) void k_matmul(const float* __restrict__ X,
                                                const float* __restrict__ W,
                                                const float* __restrict__ dinv,
                                                float* __restrict__ H, int n) {
    constexpr int KS = 64;                    // k per stage
    __shared__ __align__(16) float Xs[KS * 68];   // [k][swizzled row quad]
    __shared__ __align__(16) float Ws[K * 64];    // [k][col]
    const int t = threadIdx.x;
    const int rowBase = blockIdx.x * 64;

#pragma unroll
    for (int i = t; i < K * 16; i += 256)
        reinterpret_cast<float4*>(Ws)[i] = reinterpret_cast<const float4*>(W)[i];

    const int cg = t & 15;
    const int rg = t >> 4;
    float acc[4][4] = {{0.f}};

    for (int k0 = 0; k0 < K; k0 += KS) {
        __syncthreads();
        for (int i = t; i < 64 * (KS / 4); i += 256) {
            int r = i / (KS / 4);
            int q = i - r * (KS / 4);
            int gr = rowBase + r;
            float4 v = make_float4(0.f, 0.f, 0.f, 0.f);
            if (gr < n) v = reinterpret_cast<const float4*>(X)[(size_t)gr * (K / 4) + (k0 / 4) + q];
            int g2 = (((r >> 2) ^ (q & 15)) << 2) + (r & 3);
            int kk = q * 4;
            Xs[(kk + 0) * 68 + g2] = v.x;
            Xs[(kk + 1) * 68 + g2] = v.y;
            Xs[(kk + 2) * 68 + g2] = v.z;
            Xs[(kk + 3) * 68 + g2] = v.w;
        }
        __syncthreads();
#pragma unroll 4
        for (int kk = 0; kk < KS; kk++) {
            const float4 xv = *reinterpret_cast<const float4*>(
                &Xs[kk * 68 + ((rg ^ ((kk >> 2) & 15)) << 2)]);
            const float4 wv = *reinterpret_cast<const float4*>(
                &Ws[(k0 + kk) * 64 + 4 * cg]);
            const float xa[4] = {xv.x, xv.y, xv.z, xv.w};
            const float wa[4] = {wv.x, wv.y, wv.z, wv.w};
#pragma unroll
            for (int i = 0; i < 4; i++)
#pragma unroll
                for (int j = 0; j < 4; j++)
                    acc[i][j] = fmaf(xa[i], wa[j], acc[i][j]);
        }
    }

#pragma unroll
    for (int i = 0; i < 4; i++) {
        int gr = rowBase + 4 * rg + i;
        if (gr < n) {
            float dv = dinv[gr];
            float4 o = make_float4(acc[i][0] * dv, acc[i][1] * dv,
                                   acc[i][2] * dv, acc[i][3] * dv);
            reinterpret_cast<float4*>(H)[(size_t)gr * 16 + cg] = o;
        }
    }
}

// --- aggregate: out[c] = relu(dinv[c]*(sum ew*h'[src] + h'[c]) + b) ---------
// wave = (node, half-row). half = blockIdx.x & 1 -> under round-robin
// dispatch each XCD touches only one 128B half-line per h row. Lanes =
// 2 edge-parities x 32 channels; 8 accumulators = 16 edges in flight.
__global__ __launch_bounds__(256) void k_aggregate(
    const float* __restrict__ hp, const int* __restrict__ offs,
    const int* __restrict__ cnt, const int2* __restrict__ csr,
    const float* __restrict__ dinv, const float* __restrict__ bias,
    float* __restrict__ out, int n) {
    const int lane = threadIdx.x & 63;
    const int epar = lane >> 5;            // which edge of the pair
    const int half = blockIdx.x & 1;       // which 128B half of the row
    const int cb   = half * 32 + (lane & 31);  // absolute channel
    const int node = (blockIdx.x >> 1) * 4 + (threadIdx.x >> 6);
    if (node >= n) return;
    const int c = cnt[node];
    const int s = offs[node];

    // stage up to 64 CSR entries across lanes; pad = (self, 0.0) -> no-op
    int2 mc = make_int2(node, 0);
    if (lane < c) mc = csr[s + lane];
    const int cc = min(c, 64);
    const int npairs = (cc + 1) >> 1;
    const int p8 = (npairs + 7) & ~7;

    float a0 = 0.f, a1 = 0.f, a2 = 0.f, a3 = 0.f;
    float a4 = 0.f, a5 = 0.f, a6 = 0.f, a7 = 0.f;

    for (int p = 0; p < p8; p += 8) {
        int i0 = 2 * p + epar;
        int s0 = __shfl(mc.x, i0 +  0), w0 = __shfl(mc.y, i0 +  0);
        int s1 = __shfl(mc.x, i0 +  2), w1 = __shfl(mc.y, i0 +  2);
        int s2 = __shfl(mc.x, i0 +  4), w2 = __shfl(mc.y, i0 +  4);
        int s3 = __shfl(mc.x, i0 +  6), w3 = __shfl(mc.y, i0 +  6);
        int s4 = __shfl(mc.x, i0 +  8), w4 = __shfl(mc.y, i0 +  8);
        int s5 = __shfl(mc.x, i0 + 10), w5 = __shfl(mc.y, i0 + 10);
        int s6 = __shfl(mc.x, i0 + 12), w6 = __shfl(mc.y, i0 + 12);
        int s7 = __shfl(mc.x, i0 + 14), w7 = __shfl(mc.y, i0 + 14);
        float v0 = hp[(size_t)s0 * 64 + cb];
        float v1 = hp[(size_t)s1 * 64 + cb];
        float v2 = hp[(size_t)s2 * 64 + cb];
        float v3 = hp[(size_t)s3 * 64 + cb];
        float v4 = hp[(size_t)s4 * 64 + cb];
        float v5 = hp[(size_t)s5 * 64 + cb];
        float v6 = hp[(size_t)s6 * 64 + cb];
        float v7 = hp[(size_t)s7 * 64 + cb];
        a0 = fmaf(v0, __int_as_float(w0), a0);
        a1 = fmaf(v1, __int_as_float(w1), a1);
        a2 = fmaf(v2, __int_as_float(w2), a2);
        a3 = fmaf(v3, __int_as_float(w3), a3);
        a4 = fmaf(v4, __int_as_float(w4), a4);
        a5 = fmaf(v5, __int_as_float(w5), a5);
        a6 = fmaf(v6, __int_as_float(w6), a6);
        a7 = fmaf(v7, __int_as_float(w7), a7);
    }
    float t = (((a0 + a1) + (a2 + a3)) + ((a4 + a5) + (a6 + a7)));
    t += __shfl(t, lane ^ 32);           // combine edge parities

    // rare overflow (deg > 64): uniform csr read, scalar gather
    for (int j = 64; j < c; ++j) {
        int2 e = csr[s + j];
        t = fmaf(hp[(size_t)e.x * 64 + cb], __int_as_float(e.y), t);
    }

    if (epar == 0) {
        float self = hp[(size_t)node * 64 + cb];
        float r = fmaf(t + self, dinv[node], bias[cb]);
        out[(size_t)node * 64 + cb] = fmaxf(r, 0.0f);
    }
}

// --- mean pool per graph + fused MLP head ------------------------------------
__global__ __launch_bounds__(1024) void k_pool_head(
    const float* __restrict__ h, const int* __restrict__ batch, int n,
    const float* __restrict__ Wc1, const float* __restrict__ bc1,
    const float* __restrict__ Wc2, const float* __restrict__ bc2,
    float* __restrict__ out) {
    const int g = blockIdx.x;
    const int t = threadIdx.x;
    const int lane = t & 63, w = t >> 6;   // 16 waves
    __shared__ float sums[16][64];
    __shared__ float pooled[64];
    __shared__ float z[32];

    int start = lower_bound_i(batch, n, g);
    int end   = lower_bound_i(batch, n, g + 1);

    float acc = 0.f;
    for (int i = start + w; i < end; i += 16)
        acc += h[(size_t)i * 64 + lane];
    sums[w][lane] = acc;
    __syncthreads();
    if (w == 0) {
        float v = 0.f;
#pragma unroll
        for (int k = 0; k < 16; k++) v += sums[k][lane];
        float c = (float)(end - start);
        pooled[lane] = v / fmaxf(c, 1.0f);
    }
    __syncthreads();
    if (t < 32) {
        float a = bc1[t];
        for (int k = 0; k < 64; k++) a = fmaf(pooled[k], Wc1[k * 32 + t], a);
        z[t] = fmaxf(a, 0.f);
    }
    __syncthreads();
    if (t < 10) {
        float a = bc2[t];
        for (int k = 0; k < 32; k++) a = fmaf(z[k], Wc2[k * 10 + t], a);
        out[g * 10 + t] = a;
    }
}

// ---------------------------------------------------------------------------
extern "C" void kernel_launch(void* const* d_in, const int* in_sizes, int n_in,
                              void* d_out, int out_size, void* d_ws, size_t ws_size,
                              hipStream_t stream) {
    const float* x    = (const float*)d_in[0];
    const int*   ei   = (const int*)d_in[1];
    const float* ew   = (const float*)d_in[2];
    const int*   bat  = (const int*)d_in[3];
    const float* W1   = (const float*)d_in[4];
    const float* b1   = (const float*)d_in[5];
    const float* W2   = (const float*)d_in[6];
    const float* b2   = (const float*)d_in[7];
    const float* Wc1  = (const float*)d_in[8];
    const float* bc1  = (const float*)d_in[9];
    const float* Wc2  = (const float*)d_in[10];
    const float* bc2  = (const float*)d_in[11];
    float* out = (float*)d_out;

    const int N = in_sizes[0] / 128;
    const int E = in_sizes[2];
    const int G = out_size / 10;
    const int K = (N + 255) >> BKT_BITS;          // buckets of 256 nodes
    const int KB = K * PART_BLOCKS;               // histogram elements
    const int CH = (E + PART_BLOCKS - 1) / PART_BLOCKS;  // edges per partition block

    const int* row = ei;
    const int* col = ei + E;

    // workspace carve-up (256B aligned slices)
    char* p = (char*)d_ws;
    auto alloc = [&](size_t bytes) -> void* {
        void* r = (void*)p;
        p += (bytes + 255) & ~(size_t)255;
        return r;
    };
    int*   bh    = (int*)  alloc((size_t)KB * 4);
    int*   bhs   = (int*)  alloc((size_t)KB * 4);
    int*   bsums = (int*)  alloc(8192);
    int*   offs  = (int*)  alloc((size_t)N * 4);
    int*   cnt   = (int*)  alloc((size_t)N * 4);
    float* dinv  = (float*)alloc((size_t)N * 4);
    int2*  csr   = (int2*) alloc((size_t)E * 8);
    // h aliases the partition arrays (part2/partc dead before matmul1 runs)
    char*  hbase = (char*) alloc((size_t)N * 64 * 4 > (size_t)E * 12 ? (size_t)N * 64 * 4
                                                                     : (size_t)E * 12);
    float* o     = (float*)alloc((size_t)N * 64 * 4);
    int2*  part2 = (int2*) hbase;
    int*   partc = (int*)  (hbase + (size_t)E * 8);
    float* h     = (float*)hbase;

    const int NB = (KB + 1023) / 1024;

    // CSR build: zero global atomics
    k_histA<<<PART_BLOCKS, 256, 0, stream>>>(col, E, CH, K, bh);
    k_scan_partial<<<NB, TPB, 0, stream>>>(bh, bsums, KB);
    k_scan_bsums<<<1, 64, 0, stream>>>(bsums, NB);
    k_scan_final<<<NB, TPB, 0, stream>>>(bh, bsums, bhs, KB);
    k_partB<<<PART_BLOCKS, 256, 0, stream>>>(row, col, ew, bhs, E, CH, K, part2, partc);
    k_csrC<<<K, 256, 0, stream>>>(part2, partc, bhs, K, N, E, offs, cnt, dinv, csr);

    const int gb_mm = (N + 63) / 64;
    const int gb_ag = 2 * ((N + 3) / 4);   // x2: (node-group, half) blocks

    // layer 1
    k_matmul<128><<<gb_mm, 256, 0, stream>>>(x, W1, dinv, h, N);
    k_aggregate<<<gb_ag, 256, 0, stream>>>(h, offs, cnt, csr, dinv, b1, o, N);
    // layer 2
    k_matmul<64><<<gb_mm, 256, 0, stream>>>(o, W2, dinv, h, N);
    k_aggregate<<<gb_ag, 256, 0, stream>>>(h, offs, cnt, csr, dinv, b2, o, N);
    // pool + head
    k_pool_head<<<G, 1024, 0, stream>>>(o, bat, N, Wc1, bc1, Wc2, bc2, out);
}

// Round 8
// 215.432 us; speedup vs baseline: 1.2718x; 1.2718x over previous
//
#include <hip/hip_runtime.h>
#include <hip/hip_fp16.h>

// ---------------------------------------------------------------------------
// SimpleGCN: 2x GCNConv (self-loops, symmetric norm) + mean pool + MLP head
// N=100000 nodes, E=1.6M edges, IN=128, HID=64, G=128 graphs, NCLS=10
//
// Round 7: R6's channel-split reverted (regression: weak XCD mapping, 2x
// VALU). New lever: the aggregate is fetch-service-bound on ~195MB of
// structural cross-XCD traffic (each 256B fp32 row = 2 lines, every XCD
// touches ~all rows). Store the gathered operand h' = dinv(.)(XW) in FP16:
// one row = 64 halves = 128B = ONE line -> gather traffic halves. All
// accumulation / CSR / layer outputs / pooling stay fp32; only gathered
// values are quantized (error averages out in the mean-pool, ~1e-6..1e-5
// final vs 3.6e-5 threshold). Aggregate: wave/node, lanes = 2 edge-parities
// x 32 channel-pairs (half2); one wave load = 2 edge rows; 16 edges in
// flight via 8 independent accumulator pairs.
// ---------------------------------------------------------------------------

#define TPB 256
#define FIX_SCALE 16777216.0f   // 2^24
#define BKT_BITS 8              // bucket = 256 nodes
#define PART_BLOCKS 256         // blocks in hist/partition passes

__device__ __forceinline__ int lower_bound_i(const int* __restrict__ a, int n, int key) {
    int lo = 0, hi = n;
    while (lo < hi) {
        int mid = (lo + hi) >> 1;
        if (a[mid] < key) lo = mid + 1; else hi = mid;
    }
    return lo;
}

// --- A. per-block bucket histogram ------------------------------------------
__global__ __launch_bounds__(256) void k_histA(const int* __restrict__ col, int E, int CH,
                                               int K, int* __restrict__ bh) {
    __shared__ int hist[512];
    int b = blockIdx.x, t = threadIdx.x;
    for (int i = t; i < K; i += 256) hist[i] = 0;
    __syncthreads();
    int s = b * CH, e = min(E, s + CH);
    for (int i = s + t; i < e; i += 256) atomicAdd(&hist[col[i] >> BKT_BITS], 1);
    __syncthreads();
    for (int i = t; i < K; i += 256) bh[i * PART_BLOCKS + b] = hist[i];
}

// --- scan (1024 elems per block) ---------------------------------------------
__global__ void k_scan_partial(const int* __restrict__ cnt, int* __restrict__ bsums, int n) {
    __shared__ int red[4];
    int b = blockIdx.x, t = threadIdx.x;
    int base = b * 1024;
    int s = 0;
#pragma unroll
    for (int i = 0; i < 4; i++) {
        int idx = base + t + i * TPB;
        if (idx < n) s += cnt[idx];
    }
#pragma unroll
    for (int off = 32; off > 0; off >>= 1) s += __shfl_down(s, off);
    if ((t & 63) == 0) red[t >> 6] = s;
    __syncthreads();
    if (t == 0) bsums[b] = red[0] + red[1] + red[2] + red[3];
}

__global__ void k_scan_bsums(int* __restrict__ bsums, int nb) {
    int l = threadIdx.x;
    int carry = 0;
    for (int base = 0; base < nb; base += 64) {
        int i = base + l;
        int v = (i < nb) ? bsums[i] : 0;
        int orig = v;
#pragma unroll
        for (int off = 1; off < 64; off <<= 1) {
            int x = __shfl_up(v, off);
            if (l >= off) v += x;
        }
        if (i < nb) bsums[i] = v - orig + carry;  // exclusive + carry
        carry += __shfl(v, 63);
    }
}

__global__ void k_scan_final(const int* __restrict__ cnt, const int* __restrict__ boffs,
                             int* __restrict__ offs, int n) {
    __shared__ int ts[TPB];
    int b = blockIdx.x, t = threadIdx.x;
    int base = b * 1024 + 4 * t;
    int v[4]; int s = 0;
#pragma unroll
    for (int i = 0; i < 4; i++) {
        int idx = base + i;
        v[i] = (idx < n) ? cnt[idx] : 0;
        s += v[i];
    }
    ts[t] = s; __syncthreads();
    for (int off = 1; off < 256; off <<= 1) {
        int x = (t >= off) ? ts[t - off] : 0;
        __syncthreads();
        ts[t] += x;
        __syncthreads();
    }
    int run = ts[t] - s + boffs[b];
#pragma unroll
    for (int i = 0; i < 4; i++) {
        int idx = base + i;
        if (idx < n) offs[idx] = run;
        run += v[i];
    }
}

// --- C. partition edges by bucket (LDS cursors, no global atomics) ----------
__global__ __launch_bounds__(256) void k_partB(const int* __restrict__ row,
                                               const int* __restrict__ col,
                                               const float* __restrict__ ew,
                                               const int* __restrict__ bhs,
                                               int E, int CH, int K,
                                               int2* __restrict__ part2,
                                               int* __restrict__ partc) {
    __shared__ int cur[512];
    int b = blockIdx.x, t = threadIdx.x;
    for (int i = t; i < K; i += 256) cur[i] = bhs[i * PART_BLOCKS + b];
    __syncthreads();
    int s = b * CH, e = min(E, s + CH);
    for (int i = s + t; i < e; i += 256) {
        int c = col[i];
        int pos = atomicAdd(&cur[c >> BKT_BITS], 1);
        part2[pos] = make_int2(row[i], __float_as_int(ew[i]));
        partc[pos] = c;
    }
}

// --- D. per-bucket CSR finalize ----------------------------------------------
__global__ __launch_bounds__(256) void k_csrC(const int2* __restrict__ part2,
                                              const int* __restrict__ partc,
                                              const int* __restrict__ bhs,
                                              int K, int N, int E,
                                              int* __restrict__ offs, int* __restrict__ cnt,
                                              float* __restrict__ dinv,
                                              int2* __restrict__ csr) {
    __shared__ int lcnt[256];
    __shared__ unsigned lew[256];
    __shared__ int lcur[256];
    __shared__ int ts[256];
    int k = blockIdx.x, t = threadIdx.x;
    int n0 = k << BKT_BITS;
    lcnt[t] = 0; lew[t] = 0;
    __syncthreads();
    int estart = bhs[k * PART_BLOCKS];
    int eend   = (k + 1 < K) ? bhs[(k + 1) * PART_BLOCKS] : E;
    for (int i = estart + t; i < eend; i += 256) {
        int c = partc[i] - n0;
        atomicAdd(&lcnt[c], 1);
        float w = __int_as_float(part2[i].y);
        atomicAdd(&lew[c], (unsigned)(w * FIX_SCALE + 0.5f));
    }
    __syncthreads();
    int myc = lcnt[t];
    ts[t] = myc; __syncthreads();
    for (int off = 1; off < 256; off <<= 1) {
        int x = (t >= off) ? ts[t - off] : 0;
        __syncthreads();
        ts[t] += x;
        __syncthreads();
    }
    int goff = estart + ts[t] - myc;   // global CSR offset for node n0+t
    int node = n0 + t;
    if (node < N) {
        offs[node] = goff;
        cnt[node]  = myc;
        float deg = 1.0f + (float)((double)lew[t] * (1.0 / 16777216.0));
        dinv[node] = 1.0f / sqrtf(deg);
    }
    lcur[t] = goff;
    __syncthreads();
    for (int i = estart + t; i < eend; i += 256) {
        int c = partc[i] - n0;
        int pos = atomicAdd(&lcur[c], 1);
        csr[pos] = part2[i];
    }
}

// --- matmul: Hh[n,64] (fp16) = dinv (.) (X[n,K] @ W[K,64]) ------------------
template <int K>
__global__ __launch_bounds__(256) void k_matmul(const float* __restrict__ X,
                                                const float* __restrict__ W,
                                                const float* __restrict__ dinv,
                                                __half* __restrict__ Hh, int n) {
    constexpr int KS = 64;                    // k per stage
    __shared__ __align__(16) float Xs[KS * 68];   // [k][swizzled row quad]
    __shared__ __align__(16) float Ws[K * 64];    // [k][col]
    const int t = threadIdx.x;
    const int rowBase = blockIdx.x * 64;

#pragma unroll
    for (int i = t; i < K * 16; i += 256)
        reinterpret_cast<float4*>(Ws)[i] = reinterpret_cast<const float4*>(W)[i];

    const int cg = t & 15;
    const int rg = t >> 4;
    float acc[4][4] = {{0.f}};

    for (int k0 = 0; k0 < K; k0 += KS) {
        __syncthreads();
        for (int i = t; i < 64 * (KS / 4); i += 256) {
            int r = i / (KS / 4);
            int q = i - r * (KS / 4);
            int gr = rowBase + r;
            float4 v = make_float4(0.f, 0.f, 0.f, 0.f);
            if (gr < n) v = reinterpret_cast<const float4*>(X)[(size_t)gr * (K / 4) + (k0 / 4) + q];
            int g2 = (((r >> 2) ^ (q & 15)) << 2) + (r & 3);
            int kk = q * 4;
            Xs[(kk + 0) * 68 + g2] = v.x;
            Xs[(kk + 1) * 68 + g2] = v.y;
            Xs[(kk + 2) * 68 + g2] = v.z;
            Xs[(kk + 3) * 68 + g2] = v.w;
        }
        __syncthreads();
#pragma unroll 4
        for (int kk = 0; kk < KS; kk++) {
            const float4 xv = *reinterpret_cast<const float4*>(
                &Xs[kk * 68 + ((rg ^ ((kk >> 2) & 15)) << 2)]);
            const float4 wv = *reinterpret_cast<const float4*>(
                &Ws[(k0 + kk) * 64 + 4 * cg]);
            const float xa[4] = {xv.x, xv.y, xv.z, xv.w};
            const float wa[4] = {wv.x, wv.y, wv.z, wv.w};
#pragma unroll
            for (int i = 0; i < 4; i++)
#pragma unroll
                for (int j = 0; j < 4; j++)
                    acc[i][j] = fmaf(xa[i], wa[j], acc[i][j]);
        }
    }

#pragma unroll
    for (int i = 0; i < 4; i++) {
        int gr = rowBase + 4 * rg + i;
        if (gr < n) {
            float dv = dinv[gr];
            __half2 p0 = __floats2half2_rn(acc[i][0] * dv, acc[i][1] * dv);
            __half2 p1 = __floats2half2_rn(acc[i][2] * dv, acc[i][3] * dv);
            uint2 u = make_uint2(*reinterpret_cast<unsigned*>(&p0),
                                 *reinterpret_cast<unsigned*>(&p1));
            *reinterpret_cast<uint2*>(&Hh[(size_t)gr * 64 + 4 * cg]) = u;
        }
    }
}

// --- aggregate: out[c] = relu(dinv[c]*(sum ew*h'[src] + h'[c]) + b) ---------
// hp is fp16 [N][64] = one 128B line per row. Wave per node; lanes =
// 2 edge-parities x 32 channel-pairs (half2). One wave-wide load = two
// edges' rows; 8 accumulator pairs = 16 edges in flight. Accumulate fp32.
__global__ __launch_bounds__(256) void k_aggregate(
    const __half2* __restrict__ hp2, const int* __restrict__ offs,
    const int* __restrict__ cnt, const int2* __restrict__ csr,
    const float* __restrict__ dinv, const float* __restrict__ bias,
    float* __restrict__ out, int n) {
    const int lane = threadIdx.x & 63;
    const int epar = lane >> 5;          // which edge of the pair
    const int lpos = lane & 31;          // channel-pair index (2 ch per lane)
    const int node = blockIdx.x * 4 + (threadIdx.x >> 6);
    if (node >= n) return;
    const int c = cnt[node];
    const int s = offs[node];

    // stage up to 64 CSR entries across lanes; pad = (self, 0.0) -> no-op
    int2 mc = make_int2(node, 0);
    if (lane < c) mc = csr[s + lane];
    const int cc = min(c, 64);
    const int npairs = (cc + 1) >> 1;
    const int p8 = (npairs + 7) & ~7;

    float ax[8] = {0.f, 0.f, 0.f, 0.f, 0.f, 0.f, 0.f, 0.f};
    float ay[8] = {0.f, 0.f, 0.f, 0.f, 0.f, 0.f, 0.f, 0.f};

    for (int p = 0; p < p8; p += 8) {
#pragma unroll
        for (int i = 0; i < 8; i++) {
            int idx = 2 * (p + i) + epar;          // per-half edge index (<=63)
            int src = __shfl(mc.x, idx);
            float w = __int_as_float(__shfl(mc.y, idx));
            float2 f = __half22float2(hp2[(size_t)src * 32 + lpos]);
            ax[i] = fmaf(f.x, w, ax[i]);
            ay[i] = fmaf(f.y, w, ay[i]);
        }
    }
    // reduce 8 accumulators, then combine edge parities
    float tx = ((ax[0] + ax[1]) + (ax[2] + ax[3])) + ((ax[4] + ax[5]) + (ax[6] + ax[7]));
    float ty = ((ay[0] + ay[1]) + (ay[2] + ay[3])) + ((ay[4] + ay[5]) + (ay[6] + ay[7]));
    tx += __shfl(tx, lane ^ 32);
    ty += __shfl(ty, lane ^ 32);

    // rare overflow (deg > 64): uniform csr read
    for (int j = 64; j < c; ++j) {
        int2 e = csr[s + j];
        float2 f = __half22float2(hp2[(size_t)e.x * 32 + lpos]);
        float w = __int_as_float(e.y);
        tx = fmaf(f.x, w, tx);
        ty = fmaf(f.y, w, ty);
    }

    if (epar == 0) {
        float2 sv = __half22float2(hp2[(size_t)node * 32 + lpos]);
        const float2 bv = *reinterpret_cast<const float2*>(&bias[lpos * 2]);
        float dv = dinv[node];
        float rx = fmaf(tx + sv.x, dv, bv.x);
        float ry = fmaf(ty + sv.y, dv, bv.y);
        float2 o = make_float2(fmaxf(rx, 0.f), fmaxf(ry, 0.f));
        *reinterpret_cast<float2*>(&out[(size_t)node * 64 + lpos * 2]) = o;
    }
}

// --- mean pool per graph + fused MLP head ------------------------------------
__global__ __launch_bounds__(1024) void k_pool_head(
    const float* __restrict__ h, const int* __restrict__ batch, int n,
    const float* __restrict__ Wc1, const float* __restrict__ bc1,
    const float* __restrict__ Wc2, const float* __restrict__ bc2,
    float* __restrict__ out) {
    const int g = blockIdx.x;
    const int t = threadIdx.x;
    const int lane = t & 63, w = t >> 6;   // 16 waves
    __shared__ float sums[16][64];
    __shared__ float pooled[64];
    __shared__ float z[32];

    int start = lower_bound_i(batch, n, g);
    int end   = lower_bound_i(batch, n, g + 1);

    float acc = 0.f;
    for (int i = start + w; i < end; i += 16)
        acc += h[(size_t)i * 64 + lane];
    sums[w][lane] = acc;
    __syncthreads();
    if (w == 0) {
        float v = 0.f;
#pragma unroll
        for (int k = 0; k < 16; k++) v += sums[k][lane];
        float c = (float)(end - start);
        pooled[lane] = v / fmaxf(c, 1.0f);
    }
    __syncthreads();
    if (t < 32) {
        float a = bc1[t];
        for (int k = 0; k < 64; k++) a = fmaf(pooled[k], Wc1[k * 32 + t], a);
        z[t] = fmaxf(a, 0.f);
    }
    __syncthreads();
    if (t < 10) {
        float a = bc2[t];
        for (int k = 0; k < 32; k++) a = fmaf(z[k], Wc2[k * 10 + t], a);
        out[g * 10 + t] = a;
    }
}

// ---------------------------------------------------------------------------
extern "C" void kernel_launch(void* const* d_in, const int* in_sizes, int n_in,
                              void* d_out, int out_size, void* d_ws, size_t ws_size,
                              hipStream_t stream) {
    const float* x    = (const float*)d_in[0];
    const int*   ei   = (const int*)d_in[1];
    const float* ew   = (const float*)d_in[2];
    const int*   bat  = (const int*)d_in[3];
    const float* W1   = (const float*)d_in[4];
    const float* b1   = (const float*)d_in[5];
    const float* W2   = (const float*)d_in[6];
    const float* b2   = (const float*)d_in[7];
    const float* Wc1  = (const float*)d_in[8];
    const float* bc1  = (const float*)d_in[9];
    const float* Wc2  = (const float*)d_in[10];
    const float* bc2  = (const float*)d_in[11];
    float* out = (float*)d_out;

    const int N = in_sizes[0] / 128;
    const int E = in_sizes[2];
    const int G = out_size / 10;
    const int K = (N + 255) >> BKT_BITS;          // buckets of 256 nodes
    const int KB = K * PART_BLOCKS;               // histogram elements
    const int CH = (E + PART_BLOCKS - 1) / PART_BLOCKS;  // edges per partition block

    const int* row = ei;
    const int* col = ei + E;

    // workspace carve-up (256B aligned slices)
    char* p = (char*)d_ws;
    auto alloc = [&](size_t bytes) -> void* {
        void* r = (void*)p;
        p += (bytes + 255) & ~(size_t)255;
        return r;
    };
    int*   bh    = (int*)  alloc((size_t)KB * 4);
    int*   bhs   = (int*)  alloc((size_t)KB * 4);
    int*   bsums = (int*)  alloc(8192);
    int*   offs  = (int*)  alloc((size_t)N * 4);
    int*   cnt   = (int*)  alloc((size_t)N * 4);
    float* dinv  = (float*)alloc((size_t)N * 4);
    int2*  csr   = (int2*) alloc((size_t)E * 8);
    // fp16 h aliases the partition arrays (part2/partc dead before matmul1)
    size_t hbytes = (size_t)N * 64 * 2;
    size_t pbytes = (size_t)E * 12;
    char*  hbase = (char*) alloc(hbytes > pbytes ? hbytes : pbytes);
    float* o     = (float*)alloc((size_t)N * 64 * 4);
    int2*  part2 = (int2*) hbase;
    int*   partc = (int*)  (hbase + (size_t)E * 8);
    __half* h    = (__half*)hbase;

    const int NB = (KB + 1023) / 1024;

    // CSR build: zero global atomics
    k_histA<<<PART_BLOCKS, 256, 0, stream>>>(col, E, CH, K, bh);
    k_scan_partial<<<NB, TPB, 0, stream>>>(bh, bsums, KB);
    k_scan_bsums<<<1, 64, 0, stream>>>(bsums, NB);
    k_scan_final<<<NB, TPB, 0, stream>>>(bh, bsums, bhs, KB);
    k_partB<<<PART_BLOCKS, 256, 0, stream>>>(row, col, ew, bhs, E, CH, K, part2, partc);
    k_csrC<<<K, 256, 0, stream>>>(part2, partc, bhs, K, N, E, offs, cnt, dinv, csr);

    const int gb_mm = (N + 63) / 64;
    const int gb_ag = (N + 3) / 4;

    // layer 1
    k_matmul<128><<<gb_mm, 256, 0, stream>>>(x, W1, dinv, h, N);
    k_aggregate<<<gb_ag, 256, 0, stream>>>((const __half2*)h, offs, cnt, csr, dinv, b1, o, N);
    // layer 2
    k_matmul<64><<<gb_mm, 256, 0, stream>>>(o, W2, dinv, h, N);
    k_aggregate<<<gb_ag, 256, 0, stream>>>((const __half2*)h, offs, cnt, csr, dinv, b2, o, N);
    // pool + head
    k_pool_head<<<G, 1024, 0, stream>>>(o, bat, N, Wc1, bc1, Wc2, bc2, out);
}

// Round 9
// 200.897 us; speedup vs baseline: 1.3638x; 1.0723x over previous
//
#include <hip/hip_runtime.h>
#include <hip/hip_fp16.h>

// ---------------------------------------------------------------------------
// SimpleGCN: 2x GCNConv (self-loops, symmetric norm) + mean pool + MLP head
// N=100000 nodes, E=1.6M edges, IN=128, HID=64, G=128 graphs, NCLS=10
//
// Round 8 change: k_partB was scattered-write-amplification-bound (WRITE
// 77MB vs 19MB logical: 391 open regions x 2 arrays x 256 blocks overflowed
// per-XCD L2 -> partial-line evictions). Pack the partition record into ONE
// int2: x = row | (c_local << 20)  (row < 2^20, c_local = c & 255), y = ew
// bits. partc[] is gone: 8B/edge single-array writes, half the open-region
// footprint -> fits L2 -> ~1x write amplification. csrC unpacks c_local
// from x>>20 and masks row for the final CSR.
// ---------------------------------------------------------------------------

#define TPB 256
#define FIX_SCALE 16777216.0f   // 2^24
#define BKT_BITS 8              // bucket = 256 nodes
#define PART_BLOCKS 256         // blocks in hist/partition passes

__device__ __forceinline__ int lower_bound_i(const int* __restrict__ a, int n, int key) {
    int lo = 0, hi = n;
    while (lo < hi) {
        int mid = (lo + hi) >> 1;
        if (a[mid] < key) lo = mid + 1; else hi = mid;
    }
    return lo;
}

// --- A. per-block bucket histogram ------------------------------------------
__global__ __launch_bounds__(256) void k_histA(const int* __restrict__ col, int E, int CH,
                                               int K, int* __restrict__ bh) {
    __shared__ int hist[512];
    int b = blockIdx.x, t = threadIdx.x;
    for (int i = t; i < K; i += 256) hist[i] = 0;
    __syncthreads();
    int s = b * CH, e = min(E, s + CH);
    for (int i = s + t; i < e; i += 256) atomicAdd(&hist[col[i] >> BKT_BITS], 1);
    __syncthreads();
    for (int i = t; i < K; i += 256) bh[i * PART_BLOCKS + b] = hist[i];
}

// --- scan (1024 elems per block) ---------------------------------------------
__global__ void k_scan_partial(const int* __restrict__ cnt, int* __restrict__ bsums, int n) {
    __shared__ int red[4];
    int b = blockIdx.x, t = threadIdx.x;
    int base = b * 1024;
    int s = 0;
#pragma unroll
    for (int i = 0; i < 4; i++) {
        int idx = base + t + i * TPB;
        if (idx < n) s += cnt[idx];
    }
#pragma unroll
    for (int off = 32; off > 0; off >>= 1) s += __shfl_down(s, off);
    if ((t & 63) == 0) red[t >> 6] = s;
    __syncthreads();
    if (t == 0) bsums[b] = red[0] + red[1] + red[2] + red[3];
}

__global__ void k_scan_bsums(int* __restrict__ bsums, int nb) {
    int l = threadIdx.x;
    int carry = 0;
    for (int base = 0; base < nb; base += 64) {
        int i = base + l;
        int v = (i < nb) ? bsums[i] : 0;
        int orig = v;
#pragma unroll
        for (int off = 1; off < 64; off <<= 1) {
            int x = __shfl_up(v, off);
            if (l >= off) v += x;
        }
        if (i < nb) bsums[i] = v - orig + carry;  // exclusive + carry
        carry += __shfl(v, 63);
    }
}

__global__ void k_scan_final(const int* __restrict__ cnt, const int* __restrict__ boffs,
                             int* __restrict__ offs, int n) {
    __shared__ int ts[TPB];
    int b = blockIdx.x, t = threadIdx.x;
    int base = b * 1024 + 4 * t;
    int v[4]; int s = 0;
#pragma unroll
    for (int i = 0; i < 4; i++) {
        int idx = base + i;
        v[i] = (idx < n) ? cnt[idx] : 0;
        s += v[i];
    }
    ts[t] = s; __syncthreads();
    for (int off = 1; off < 256; off <<= 1) {
        int x = (t >= off) ? ts[t - off] : 0;
        __syncthreads();
        ts[t] += x;
        __syncthreads();
    }
    int run = ts[t] - s + boffs[b];
#pragma unroll
    for (int i = 0; i < 4; i++) {
        int idx = base + i;
        if (idx < n) offs[idx] = run;
        run += v[i];
    }
}

// --- C. partition edges by bucket (LDS cursors; packed 8B record) -----------
__global__ __launch_bounds__(256) void k_partB(const int* __restrict__ row,
                                               const int* __restrict__ col,
                                               const float* __restrict__ ew,
                                               const int* __restrict__ bhs,
                                               int E, int CH, int K,
                                               int2* __restrict__ part2) {
    __shared__ int cur[512];
    int b = blockIdx.x, t = threadIdx.x;
    for (int i = t; i < K; i += 256) cur[i] = bhs[i * PART_BLOCKS + b];
    __syncthreads();
    int s = b * CH, e = min(E, s + CH);
    for (int i = s + t; i < e; i += 256) {
        int c = col[i];
        int pos = atomicAdd(&cur[c >> BKT_BITS], 1);
        part2[pos] = make_int2(row[i] | ((c & 255) << 20), __float_as_int(ew[i]));
    }
}

// --- D. per-bucket CSR finalize ----------------------------------------------
__global__ __launch_bounds__(256) void k_csrC(const int2* __restrict__ part2,
                                              const int* __restrict__ bhs,
                                              int K, int N, int E,
                                              int* __restrict__ offs, int* __restrict__ cnt,
                                              float* __restrict__ dinv,
                                              int2* __restrict__ csr) {
    __shared__ int lcnt[256];
    __shared__ unsigned lew[256];
    __shared__ int lcur[256];
    __shared__ int ts[256];
    int k = blockIdx.x, t = threadIdx.x;
    int n0 = k << BKT_BITS;
    lcnt[t] = 0; lew[t] = 0;
    __syncthreads();
    int estart = bhs[k * PART_BLOCKS];
    int eend   = (k + 1 < K) ? bhs[(k + 1) * PART_BLOCKS] : E;
    for (int i = estart + t; i < eend; i += 256) {
        int2 v = part2[i];
        int c = (v.x >> 20) & 255;
        atomicAdd(&lcnt[c], 1);
        float w = __int_as_float(v.y);
        atomicAdd(&lew[c], (unsigned)(w * FIX_SCALE + 0.5f));
    }
    __syncthreads();
    int myc = lcnt[t];
    ts[t] = myc; __syncthreads();
    for (int off = 1; off < 256; off <<= 1) {
        int x = (t >= off) ? ts[t - off] : 0;
        __syncthreads();
        ts[t] += x;
        __syncthreads();
    }
    int goff = estart + ts[t] - myc;   // global CSR offset for node n0+t
    int node = n0 + t;
    if (node < N) {
        offs[node] = goff;
        cnt[node]  = myc;
        float deg = 1.0f + (float)((double)lew[t] * (1.0 / 16777216.0));
        dinv[node] = 1.0f / sqrtf(deg);
    }
    lcur[t] = goff;
    __syncthreads();
    for (int i = estart + t; i < eend; i += 256) {
        int2 v = part2[i];
        int c = (v.x >> 20) & 255;
        int pos = atomicAdd(&lcur[c], 1);
        csr[pos] = make_int2(v.x & 0xFFFFF, v.y);
    }
}

// --- matmul: Hh[n,64] (fp16) = dinv (.) (X[n,K] @ W[K,64]) ------------------
template <int K>
__global__ __launch_bounds__(256) void k_matmul(const float* __restrict__ X,
                                                const float* __restrict__ W,
                                                const float* __restrict__ dinv,
                                                __half* __restrict__ Hh, int n) {
    constexpr int KS = 64;                    // k per stage
    __shared__ __align__(16) float Xs[KS * 68];   // [k][swizzled row quad]
    __shared__ __align__(16) float Ws[K * 64];    // [k][col]
    const int t = threadIdx.x;
    const int rowBase = blockIdx.x * 64;

#pragma unroll
    for (int i = t; i < K * 16; i += 256)
        reinterpret_cast<float4*>(Ws)[i] = reinterpret_cast<const float4*>(W)[i];

    const int cg = t & 15;
    const int rg = t >> 4;
    float acc[4][4] = {{0.f}};

    for (int k0 = 0; k0 < K; k0 += KS) {
        __syncthreads();
        for (int i = t; i < 64 * (KS / 4); i += 256) {
            int r = i / (KS / 4);
            int q = i - r * (KS / 4);
            int gr = rowBase + r;
            float4 v = make_float4(0.f, 0.f, 0.f, 0.f);
            if (gr < n) v = reinterpret_cast<const float4*>(X)[(size_t)gr * (K / 4) + (k0 / 4) + q];
            int g2 = (((r >> 2) ^ (q & 15)) << 2) + (r & 3);
            int kk = q * 4;
            Xs[(kk + 0) * 68 + g2] = v.x;
            Xs[(kk + 1) * 68 + g2] = v.y;
            Xs[(kk + 2) * 68 + g2] = v.z;
            Xs[(kk + 3) * 68 + g2] = v.w;
        }
        __syncthreads();
#pragma unroll 4
        for (int kk = 0; kk < KS; kk++) {
            const float4 xv = *reinterpret_cast<const float4*>(
                &Xs[kk * 68 + ((rg ^ ((kk >> 2) & 15)) << 2)]);
            const float4 wv = *reinterpret_cast<const float4*>(
                &Ws[(k0 + kk) * 64 + 4 * cg]);
            const float xa[4] = {xv.x, xv.y, xv.z, xv.w};
            const float wa[4] = {wv.x, wv.y, wv.z, wv.w};
#pragma unroll
            for (int i = 0; i < 4; i++)
#pragma unroll
                for (int j = 0; j < 4; j++)
                    acc[i][j] = fmaf(xa[i], wa[j], acc[i][j]);
        }
    }

#pragma unroll
    for (int i = 0; i < 4; i++) {
        int gr = rowBase + 4 * rg + i;
        if (gr < n) {
            float dv = dinv[gr];
            __half2 p0 = __floats2half2_rn(acc[i][0] * dv, acc[i][1] * dv);
            __half2 p1 = __floats2half2_rn(acc[i][2] * dv, acc[i][3] * dv);
            uint2 u = make_uint2(*reinterpret_cast<unsigned*>(&p0),
                                 *reinterpret_cast<unsigned*>(&p1));
            *reinterpret_cast<uint2*>(&Hh[(size_t)gr * 64 + 4 * cg]) = u;
        }
    }
}

// --- aggregate: out[c] = relu(dinv[c]*(sum ew*h'[src] + h'[c]) + b) ---------
// hp is fp16 [N][64] = one 128B line per row. Wave per node; lanes =
// 2 edge-parities x 32 channel-pairs (half2). One wave-wide load = two
// edges' rows; 8 accumulator pairs = 16 edges in flight. Accumulate fp32.
__global__ __launch_bounds__(256) void k_aggregate(
    const __half2* __restrict__ hp2, const int* __restrict__ offs,
    const int* __restrict__ cnt, const int2* __restrict__ csr,
    const float* __restrict__ dinv, const float* __restrict__ bias,
    float* __restrict__ out, int n) {
    const int lane = threadIdx.x & 63;
    const int epar = lane >> 5;          // which edge of the pair
    const int lpos = lane & 31;          // channel-pair index (2 ch per lane)
    const int node = blockIdx.x * 4 + (threadIdx.x >> 6);
    if (node >= n) return;
    const int c = cnt[node];
    const int s = offs[node];

    // stage up to 64 CSR entries across lanes; pad = (self, 0.0) -> no-op
    int2 mc = make_int2(node, 0);
    if (lane < c) mc = csr[s + lane];
    const int cc = min(c, 64);
    const int npairs = (cc + 1) >> 1;
    const int p8 = (npairs + 7) & ~7;

    float ax[8] = {0.f, 0.f, 0.f, 0.f, 0.f, 0.f, 0.f, 0.f};
    float ay[8] = {0.f, 0.f, 0.f, 0.f, 0.f, 0.f, 0.f, 0.f};

    for (int p = 0; p < p8; p += 8) {
#pragma unroll
        for (int i = 0; i < 8; i++) {
            int idx = 2 * (p + i) + epar;          // per-half edge index (<=63)
            int src = __shfl(mc.x, idx);
            float w = __int_as_float(__shfl(mc.y, idx));
            float2 f = __half22float2(hp2[(size_t)src * 32 + lpos]);
            ax[i] = fmaf(f.x, w, ax[i]);
            ay[i] = fmaf(f.y, w, ay[i]);
        }
    }
    // reduce 8 accumulators, then combine edge parities
    float tx = ((ax[0] + ax[1]) + (ax[2] + ax[3])) + ((ax[4] + ax[5]) + (ax[6] + ax[7]));
    float ty = ((ay[0] + ay[1]) + (ay[2] + ay[3])) + ((ay[4] + ay[5]) + (ay[6] + ay[7]));
    tx += __shfl(tx, lane ^ 32);
    ty += __shfl(ty, lane ^ 32);

    // rare overflow (deg > 64): uniform csr read
    for (int j = 64; j < c; ++j) {
        int2 e = csr[s + j];
        float2 f = __half22float2(hp2[(size_t)e.x * 32 + lpos]);
        float w = __int_as_float(e.y);
        tx = fmaf(f.x, w, tx);
        ty = fmaf(f.y, w, ty);
    }

    if (epar == 0) {
        float2 sv = __half22float2(hp2[(size_t)node * 32 + lpos]);
        const float2 bv = *reinterpret_cast<const float2*>(&bias[lpos * 2]);
        float dv = dinv[node];
        float rx = fmaf(tx + sv.x, dv, bv.x);
        float ry = fmaf(ty + sv.y, dv, bv.y);
        float2 o = make_float2(fmaxf(rx, 0.f), fmaxf(ry, 0.f));
        *reinterpret_cast<float2*>(&out[(size_t)node * 64 + lpos * 2]) = o;
    }
}

// --- mean pool per graph + fused MLP head ------------------------------------
__global__ __launch_bounds__(1024) void k_pool_head(
    const float* __restrict__ h, const int* __restrict__ batch, int n,
    const float* __restrict__ Wc1, const float* __restrict__ bc1,
    const float* __restrict__ Wc2, const float* __restrict__ bc2,
    float* __restrict__ out) {
    const int g = blockIdx.x;
    const int t = threadIdx.x;
    const int lane = t & 63, w = t >> 6;   // 16 waves
    __shared__ float sums[16][64];
    __shared__ float pooled[64];
    __shared__ float z[32];

    int start = lower_bound_i(batch, n, g);
    int end   = lower_bound_i(batch, n, g + 1);

    float acc = 0.f;
    for (int i = start + w; i < end; i += 16)
        acc += h[(size_t)i * 64 + lane];
    sums[w][lane] = acc;
    __syncthreads();
    if (w == 0) {
        float v = 0.f;
#pragma unroll
        for (int k = 0; k < 16; k++) v += sums[k][lane];
        float c = (float)(end - start);
        pooled[lane] = v / fmaxf(c, 1.0f);
    }
    __syncthreads();
    if (t < 32) {
        float a = bc1[t];
        for (int k = 0; k < 64; k++) a = fmaf(pooled[k], Wc1[k * 32 + t], a);
        z[t] = fmaxf(a, 0.f);
    }
    __syncthreads();
    if (t < 10) {
        float a = bc2[t];
        for (int k = 0; k < 32; k++) a = fmaf(z[k], Wc2[k * 10 + t], a);
        out[g * 10 + t] = a;
    }
}

// ---------------------------------------------------------------------------
extern "C" void kernel_launch(void* const* d_in, const int* in_sizes, int n_in,
                              void* d_out, int out_size, void* d_ws, size_t ws_size,
                              hipStream_t stream) {
    const float* x    = (const float*)d_in[0];
    const int*   ei   = (const int*)d_in[1];
    const float* ew   = (const float*)d_in[2];
    const int*   bat  = (const int*)d_in[3];
    const float* W1   = (const float*)d_in[4];
    const float* b1   = (const float*)d_in[5];
    const float* W2   = (const float*)d_in[6];
    const float* b2   = (const float*)d_in[7];
    const float* Wc1  = (const float*)d_in[8];
    const float* bc1  = (const float*)d_in[9];
    const float* Wc2  = (const float*)d_in[10];
    const float* bc2  = (const float*)d_in[11];
    float* out = (float*)d_out;

    const int N = in_sizes[0] / 128;
    const int E = in_sizes[2];
    const int G = out_size / 10;
    const int K = (N + 255) >> BKT_BITS;          // buckets of 256 nodes
    const int KB = K * PART_BLOCKS;               // histogram elements
    const int CH = (E + PART_BLOCKS - 1) / PART_BLOCKS;  // edges per partition block

    const int* row = ei;
    const int* col = ei + E;

    // workspace carve-up (256B aligned slices)
    char* p = (char*)d_ws;
    auto alloc = [&](size_t bytes) -> void* {
        void* r = (void*)p;
        p += (bytes + 255) & ~(size_t)255;
        return r;
    };
    int*   bh    = (int*)  alloc((size_t)KB * 4);
    int*   bhs   = (int*)  alloc((size_t)KB * 4);
    int*   bsums = (int*)  alloc(8192);
    int*   offs  = (int*)  alloc((size_t)N * 4);
    int*   cnt   = (int*)  alloc((size_t)N * 4);
    float* dinv  = (float*)alloc((size_t)N * 4);
    int2*  csr   = (int2*) alloc((size_t)E * 8);
    // fp16 h aliases the partition array (part2 dead before matmul1)
    size_t hbytes = (size_t)N * 64 * 2;
    size_t pbytes = (size_t)E * 8;
    char*  hbase = (char*) alloc(hbytes > pbytes ? hbytes : pbytes);
    float* o     = (float*)alloc((size_t)N * 64 * 4);
    int2*  part2 = (int2*) hbase;
    __half* h    = (__half*)hbase;

    const int NB = (KB + 1023) / 1024;

    // CSR build: zero global atomics
    k_histA<<<PART_BLOCKS, 256, 0, stream>>>(col, E, CH, K, bh);
    k_scan_partial<<<NB, TPB, 0, stream>>>(bh, bsums, KB);
    k_scan_bsums<<<1, 64, 0, stream>>>(bsums, NB);
    k_scan_final<<<NB, TPB, 0, stream>>>(bh, bsums, bhs, KB);
    k_partB<<<PART_BLOCKS, 256, 0, stream>>>(row, col, ew, bhs, E, CH, K, part2);
    k_csrC<<<K, 256, 0, stream>>>(part2, bhs, K, N, E, offs, cnt, dinv, csr);

    const int gb_mm = (N + 63) / 64;
    const int gb_ag = (N + 3) / 4;

    // layer 1
    k_matmul<128><<<gb_mm, 256, 0, stream>>>(x, W1, dinv, h, N);
    k_aggregate<<<gb_ag, 256, 0, stream>>>((const __half2*)h, offs, cnt, csr, dinv, b1, o, N);
    // layer 2
    k_matmul<64><<<gb_mm, 256, 0, stream>>>(o, W2, dinv, h, N);
    k_aggregate<<<gb_ag, 256, 0, stream>>>((const __half2*)h, offs, cnt, csr, dinv, b2, o, N);
    // pool + head
    k_pool_head<<<G, 1024, 0, stream>>>(o, bat, N, Wc1, bc1, Wc2, bc2, out);
}

// Round 10
// 198.276 us; speedup vs baseline: 1.3819x; 1.0132x over previous
//
#include <hip/hip_runtime.h>
#include <hip/hip_fp16.h>

// ---------------------------------------------------------------------------
// SimpleGCN: 2x GCNConv (self-loops, symmetric norm) + mean pool + MLP head
// N=100000 nodes, E=1.6M edges, IN=128, HID=64, G=128 graphs, NCLS=10
//
// Round 9 change: k_matmul<128> was occupancy/latency-bound (LDS 49KB ->
// 3 blocks/CU, Occupancy 22%, VALUBusy 32%). Stage W per-KS-chunk (16KB)
// instead of whole-K (32KB): LDS 50176 -> 33792B -> 4 blocks/CU, 50%
// occupancy. W is L2-resident so the re-read per stage is free.
// ---------------------------------------------------------------------------

#define TPB 256
#define FIX_SCALE 16777216.0f   // 2^24
#define BKT_BITS 8              // bucket = 256 nodes
#define PART_BLOCKS 256         // blocks in hist/partition passes

__device__ __forceinline__ int lower_bound_i(const int* __restrict__ a, int n, int key) {
    int lo = 0, hi = n;
    while (lo < hi) {
        int mid = (lo + hi) >> 1;
        if (a[mid] < key) lo = mid + 1; else hi = mid;
    }
    return lo;
}

// --- A. per-block bucket histogram ------------------------------------------
__global__ __launch_bounds__(256) void k_histA(const int* __restrict__ col, int E, int CH,
                                               int K, int* __restrict__ bh) {
    __shared__ int hist[512];
    int b = blockIdx.x, t = threadIdx.x;
    for (int i = t; i < K; i += 256) hist[i] = 0;
    __syncthreads();
    int s = b * CH, e = min(E, s + CH);
    for (int i = s + t; i < e; i += 256) atomicAdd(&hist[col[i] >> BKT_BITS], 1);
    __syncthreads();
    for (int i = t; i < K; i += 256) bh[i * PART_BLOCKS + b] = hist[i];
}

// --- scan (1024 elems per block) ---------------------------------------------
__global__ void k_scan_partial(const int* __restrict__ cnt, int* __restrict__ bsums, int n) {
    __shared__ int red[4];
    int b = blockIdx.x, t = threadIdx.x;
    int base = b * 1024;
    int s = 0;
#pragma unroll
    for (int i = 0; i < 4; i++) {
        int idx = base + t + i * TPB;
        if (idx < n) s += cnt[idx];
    }
#pragma unroll
    for (int off = 32; off > 0; off >>= 1) s += __shfl_down(s, off);
    if ((t & 63) == 0) red[t >> 6] = s;
    __syncthreads();
    if (t == 0) bsums[b] = red[0] + red[1] + red[2] + red[3];
}

__global__ void k_scan_bsums(int* __restrict__ bsums, int nb) {
    int l = threadIdx.x;
    int carry = 0;
    for (int base = 0; base < nb; base += 64) {
        int i = base + l;
        int v = (i < nb) ? bsums[i] : 0;
        int orig = v;
#pragma unroll
        for (int off = 1; off < 64; off <<= 1) {
            int x = __shfl_up(v, off);
            if (l >= off) v += x;
        }
        if (i < nb) bsums[i] = v - orig + carry;  // exclusive + carry
        carry += __shfl(v, 63);
    }
}

__global__ void k_scan_final(const int* __restrict__ cnt, const int* __restrict__ boffs,
                             int* __restrict__ offs, int n) {
    __shared__ int ts[TPB];
    int b = blockIdx.x, t = threadIdx.x;
    int base = b * 1024 + 4 * t;
    int v[4]; int s = 0;
#pragma unroll
    for (int i = 0; i < 4; i++) {
        int idx = base + i;
        v[i] = (idx < n) ? cnt[idx] : 0;
        s += v[i];
    }
    ts[t] = s; __syncthreads();
    for (int off = 1; off < 256; off <<= 1) {
        int x = (t >= off) ? ts[t - off] : 0;
        __syncthreads();
        ts[t] += x;
        __syncthreads();
    }
    int run = ts[t] - s + boffs[b];
#pragma unroll
    for (int i = 0; i < 4; i++) {
        int idx = base + i;
        if (idx < n) offs[idx] = run;
        run += v[i];
    }
}

// --- C. partition edges by bucket (LDS cursors; packed 8B record) -----------
__global__ __launch_bounds__(256) void k_partB(const int* __restrict__ row,
                                               const int* __restrict__ col,
                                               const float* __restrict__ ew,
                                               const int* __restrict__ bhs,
                                               int E, int CH, int K,
                                               int2* __restrict__ part2) {
    __shared__ int cur[512];
    int b = blockIdx.x, t = threadIdx.x;
    for (int i = t; i < K; i += 256) cur[i] = bhs[i * PART_BLOCKS + b];
    __syncthreads();
    int s = b * CH, e = min(E, s + CH);
    for (int i = s + t; i < e; i += 256) {
        int c = col[i];
        int pos = atomicAdd(&cur[c >> BKT_BITS], 1);
        part2[pos] = make_int2(row[i] | ((c & 255) << 20), __float_as_int(ew[i]));
    }
}

// --- D. per-bucket CSR finalize ----------------------------------------------
__global__ __launch_bounds__(256) void k_csrC(const int2* __restrict__ part2,
                                              const int* __restrict__ bhs,
                                              int K, int N, int E,
                                              int* __restrict__ offs, int* __restrict__ cnt,
                                              float* __restrict__ dinv,
                                              int2* __restrict__ csr) {
    __shared__ int lcnt[256];
    __shared__ unsigned lew[256];
    __shared__ int lcur[256];
    __shared__ int ts[256];
    int k = blockIdx.x, t = threadIdx.x;
    int n0 = k << BKT_BITS;
    lcnt[t] = 0; lew[t] = 0;
    __syncthreads();
    int estart = bhs[k * PART_BLOCKS];
    int eend   = (k + 1 < K) ? bhs[(k + 1) * PART_BLOCKS] : E;
    for (int i = estart + t; i < eend; i += 256) {
        int2 v = part2[i];
        int c = (v.x >> 20) & 255;
        atomicAdd(&lcnt[c], 1);
        float w = __int_as_float(v.y);
        atomicAdd(&lew[c], (unsigned)(w * FIX_SCALE + 0.5f));
    }
    __syncthreads();
    int myc = lcnt[t];
    ts[t] = myc; __syncthreads();
    for (int off = 1; off < 256; off <<= 1) {
        int x = (t >= off) ? ts[t - off] : 0;
        __syncthreads();
        ts[t] += x;
        __syncthreads();
    }
    int goff = estart + ts[t] - myc;   // global CSR offset for node n0+t
    int node = n0 + t;
    if (node < N) {
        offs[node] = goff;
        cnt[node]  = myc;
        float deg = 1.0f + (float)((double)lew[t] * (1.0 / 16777216.0));
        dinv[node] = 1.0f / sqrtf(deg);
    }
    lcur[t] = goff;
    __syncthreads();
    for (int i = estart + t; i < eend; i += 256) {
        int2 v = part2[i];
        int c = (v.x >> 20) & 255;
        int pos = atomicAdd(&lcur[c], 1);
        csr[pos] = make_int2(v.x & 0xFFFFF, v.y);
    }
}

// --- matmul: Hh[n,64] (fp16) = dinv (.) (X[n,K] @ W[K,64]) ------------------
// Ws staged per KS-chunk (16KB) -> LDS 33792B total -> 4 blocks/CU.
template <int K>
__global__ __launch_bounds__(256, 4) void k_matmul(const float* __restrict__ X,
                                                   const float* __restrict__ W,
                                                   const float* __restrict__ dinv,
                                                   __half* __restrict__ Hh, int n) {
    constexpr int KS = 64;                    // k per stage
    __shared__ __align__(16) float Xs[KS * 68];   // [k][swizzled row quad]
    __shared__ __align__(16) float Ws[KS * 64];   // [k-local][col]
    const int t = threadIdx.x;
    const int rowBase = blockIdx.x * 64;

    const int cg = t & 15;
    const int rg = t >> 4;
    float acc[4][4] = {{0.f}};

    for (int k0 = 0; k0 < K; k0 += KS) {
        __syncthreads();
        // stage this KS-chunk of W (k-major, coalesced float4; L2-resident)
#pragma unroll
        for (int i = t; i < KS * 16; i += 256)
            reinterpret_cast<float4*>(Ws)[i] =
                reinterpret_cast<const float4*>(W)[k0 * 16 + i];
        // stage Xs: rows rowBase..+63, local k 0..KS-1, transposed + swizzled
        for (int i = t; i < 64 * (KS / 4); i += 256) {
            int r = i / (KS / 4);
            int q = i - r * (KS / 4);
            int gr = rowBase + r;
            float4 v = make_float4(0.f, 0.f, 0.f, 0.f);
            if (gr < n) v = reinterpret_cast<const float4*>(X)[(size_t)gr * (K / 4) + (k0 / 4) + q];
            int g2 = (((r >> 2) ^ (q & 15)) << 2) + (r & 3);
            int kk = q * 4;
            Xs[(kk + 0) * 68 + g2] = v.x;
            Xs[(kk + 1) * 68 + g2] = v.y;
            Xs[(kk + 2) * 68 + g2] = v.z;
            Xs[(kk + 3) * 68 + g2] = v.w;
        }
        __syncthreads();
#pragma unroll 4
        for (int kk = 0; kk < KS; kk++) {
            const float4 xv = *reinterpret_cast<const float4*>(
                &Xs[kk * 68 + ((rg ^ ((kk >> 2) & 15)) << 2)]);
            const float4 wv = *reinterpret_cast<const float4*>(
                &Ws[kk * 64 + 4 * cg]);
            const float xa[4] = {xv.x, xv.y, xv.z, xv.w};
            const float wa[4] = {wv.x, wv.y, wv.z, wv.w};
#pragma unroll
            for (int i = 0; i < 4; i++)
#pragma unroll
                for (int j = 0; j < 4; j++)
                    acc[i][j] = fmaf(xa[i], wa[j], acc[i][j]);
        }
    }

#pragma unroll
    for (int i = 0; i < 4; i++) {
        int gr = rowBase + 4 * rg + i;
        if (gr < n) {
            float dv = dinv[gr];
            __half2 p0 = __floats2half2_rn(acc[i][0] * dv, acc[i][1] * dv);
            __half2 p1 = __floats2half2_rn(acc[i][2] * dv, acc[i][3] * dv);
            uint2 u = make_uint2(*reinterpret_cast<unsigned*>(&p0),
                                 *reinterpret_cast<unsigned*>(&p1));
            *reinterpret_cast<uint2*>(&Hh[(size_t)gr * 64 + 4 * cg]) = u;
        }
    }
}

// --- aggregate: out[c] = relu(dinv[c]*(sum ew*h'[src] + h'[c]) + b) ---------
// hp is fp16 [N][64] = one 128B line per row. Wave per node; lanes =
// 2 edge-parities x 32 channel-pairs (half2). One wave-wide load = two
// edges' rows; 8 accumulator pairs = 16 edges in flight. Accumulate fp32.
__global__ __launch_bounds__(256) void k_aggregate(
    const __half2* __restrict__ hp2, const int* __restrict__ offs,
    const int* __restrict__ cnt, const int2* __restrict__ csr,
    const float* __restrict__ dinv, const float* __restrict__ bias,
    float* __restrict__ out, int n) {
    const int lane = threadIdx.x & 63;
    const int epar = lane >> 5;          // which edge of the pair
    const int lpos = lane & 31;          // channel-pair index (2 ch per lane)
    const int node = blockIdx.x * 4 + (threadIdx.x >> 6);
    if (node >= n) return;
    const int c = cnt[node];
    const int s = offs[node];

    // stage up to 64 CSR entries across lanes; pad = (self, 0.0) -> no-op
    int2 mc = make_int2(node, 0);
    if (lane < c) mc = csr[s + lane];
    const int cc = min(c, 64);
    const int npairs = (cc + 1) >> 1;
    const int p8 = (npairs + 7) & ~7;

    float ax[8] = {0.f, 0.f, 0.f, 0.f, 0.f, 0.f, 0.f, 0.f};
    float ay[8] = {0.f, 0.f, 0.f, 0.f, 0.f, 0.f, 0.f, 0.f};

    for (int p = 0; p < p8; p += 8) {
#pragma unroll
        for (int i = 0; i < 8; i++) {
            int idx = 2 * (p + i) + epar;          // per-half edge index (<=63)
            int src = __shfl(mc.x, idx);
            float w = __int_as_float(__shfl(mc.y, idx));
            float2 f = __half22float2(hp2[(size_t)src * 32 + lpos]);
            ax[i] = fmaf(f.x, w, ax[i]);
            ay[i] = fmaf(f.y, w, ay[i]);
        }
    }
    // reduce 8 accumulators, then combine edge parities
    float tx = ((ax[0] + ax[1]) + (ax[2] + ax[3])) + ((ax[4] + ax[5]) + (ax[6] + ax[7]));
    float ty = ((ay[0] + ay[1]) + (ay[2] + ay[3])) + ((ay[4] + ay[5]) + (ay[6] + ay[7]));
    tx += __shfl(tx, lane ^ 32);
    ty += __shfl(ty, lane ^ 32);

    // rare overflow (deg > 64): uniform csr read
    for (int j = 64; j < c; ++j) {
        int2 e = csr[s + j];
        float2 f = __half22float2(hp2[(size_t)e.x * 32 + lpos]);
        float w = __int_as_float(e.y);
        tx = fmaf(f.x, w, tx);
        ty = fmaf(f.y, w, ty);
    }

    if (epar == 0) {
        float2 sv = __half22float2(hp2[(size_t)node * 32 + lpos]);
        const float2 bv = *reinterpret_cast<const float2*>(&bias[lpos * 2]);
        float dv = dinv[node];
        float rx = fmaf(tx + sv.x, dv, bv.x);
        float ry = fmaf(ty + sv.y, dv, bv.y);
        float2 o = make_float2(fmaxf(rx, 0.f), fmaxf(ry, 0.f));
        *reinterpret_cast<float2*>(&out[(size_t)node * 64 + lpos * 2]) = o;
    }
}

// --- mean pool per graph + fused MLP head ------------------------------------
__global__ __launch_bounds__(1024) void k_pool_head(
    const float* __restrict__ h, const int* __restrict__ batch, int n,
    const float* __restrict__ Wc1, const float* __restrict__ bc1,
    const float* __restrict__ Wc2, const float* __restrict__ bc2,
    float* __restrict__ out) {
    const int g = blockIdx.x;
    const int t = threadIdx.x;
    const int lane = t & 63, w = t >> 6;   // 16 waves
    __shared__ float sums[16][64];
    __shared__ float pooled[64];
    __shared__ float z[32];

    int start = lower_bound_i(batch, n, g);
    int end   = lower_bound_i(batch, n, g + 1);

    float acc = 0.f;
    for (int i = start + w; i < end; i += 16)
        acc += h[(size_t)i * 64 + lane];
    sums[w][lane] = acc;
    __syncthreads();
    if (w == 0) {
        float v = 0.f;
#pragma unroll
        for (int k = 0; k < 16; k++) v += sums[k][lane];
        float c = (float)(end - start);
        pooled[lane] = v / fmaxf(c, 1.0f);
    }
    __syncthreads();
    if (t < 32) {
        float a = bc1[t];
        for (int k = 0; k < 64; k++) a = fmaf(pooled[k], Wc1[k * 32 + t], a);
        z[t] = fmaxf(a, 0.f);
    }
    __syncthreads();
    if (t < 10) {
        float a = bc2[t];
        for (int k = 0; k < 32; k++) a = fmaf(z[k], Wc2[k * 10 + t], a);
        out[g * 10 + t] = a;
    }
}

// ---------------------------------------------------------------------------
extern "C" void kernel_launch(void* const* d_in, const int* in_sizes, int n_in,
                              void* d_out, int out_size, void* d_ws, size_t ws_size,
                              hipStream_t stream) {
    const float* x    = (const float*)d_in[0];
    const int*   ei   = (const int*)d_in[1];
    const float* ew   = (const float*)d_in[2];
    const int*   bat  = (const int*)d_in[3];
    const float* W1   = (const float*)d_in[4];
    const float* b1   = (const float*)d_in[5];
    const float* W2   = (const float*)d_in[6];
    const float* b2   = (const float*)d_in[7];
    const float* Wc1  = (const float*)d_in[8];
    const float* bc1  = (const float*)d_in[9];
    const float* Wc2  = (const float*)d_in[10];
    const float* bc2  = (const float*)d_in[11];
    float* out = (float*)d_out;

    const int N = in_sizes[0] / 128;
    const int E = in_sizes[2];
    const int G = out_size / 10;
    const int K = (N + 255) >> BKT_BITS;          // buckets of 256 nodes
    const int KB = K * PART_BLOCKS;               // histogram elements
    const int CH = (E + PART_BLOCKS - 1) / PART_BLOCKS;  // edges per partition block

    const int* row = ei;
    const int* col = ei + E;

    // workspace carve-up (256B aligned slices)
    char* p = (char*)d_ws;
    auto alloc = [&](size_t bytes) -> void* {
        void* r = (void*)p;
        p += (bytes + 255) & ~(size_t)255;
        return r;
    };
    int*   bh    = (int*)  alloc((size_t)KB * 4);
    int*   bhs   = (int*)  alloc((size_t)KB * 4);
    int*   bsums = (int*)  alloc(8192);
    int*   offs  = (int*)  alloc((size_t)N * 4);
    int*   cnt   = (int*)  alloc((size_t)N * 4);
    float* dinv  = (float*)alloc((size_t)N * 4);
    int2*  csr   = (int2*) alloc((size_t)E * 8);
    // fp16 h aliases the partition array (part2 dead before matmul1)
    size_t hbytes = (size_t)N * 64 * 2;
    size_t pbytes = (size_t)E * 8;
    char*  hbase = (char*) alloc(hbytes > pbytes ? hbytes : pbytes);
    float* o     = (float*)alloc((size_t)N * 64 * 4);
    int2*  part2 = (int2*) hbase;
    __half* h    = (__half*)hbase;

    const int NB = (KB + 1023) / 1024;

    // CSR build: zero global atomics
    k_histA<<<PART_BLOCKS, 256, 0, stream>>>(col, E, CH, K, bh);
    k_scan_partial<<<NB, TPB, 0, stream>>>(bh, bsums, KB);
    k_scan_bsums<<<1, 64, 0, stream>>>(bsums, NB);
    k_scan_final<<<NB, TPB, 0, stream>>>(bh, bsums, bhs, KB);
    k_partB<<<PART_BLOCKS, 256, 0, stream>>>(row, col, ew, bhs, E, CH, K, part2);
    k_csrC<<<K, 256, 0, stream>>>(part2, bhs, K, N, E, offs, cnt, dinv, csr);

    const int gb_mm = (N + 63) / 64;
    const int gb_ag = (N + 3) / 4;

    // layer 1
    k_matmul<128><<<gb_mm, 256, 0, stream>>>(x, W1, dinv, h, N);
    k_aggregate<<<gb_ag, 256, 0, stream>>>((const __half2*)h, offs, cnt, csr, dinv, b1, o, N);
    // layer 2
    k_matmul<64><<<gb_mm, 256, 0, stream>>>(o, W2, dinv, h, N);
    k_aggregate<<<gb_ag, 256, 0, stream>>>((const __half2*)h, offs, cnt, csr, dinv, b2, o, N);
    // pool + head
    k_pool_head<<<G, 1024, 0, stream>>>(o, bat, N, Wc1, bc1, Wc2, bc2, out);
}